// Round 1
// baseline (461.506 us; speedup 1.0000x reference)
//
#include <hip/hip_runtime.h>

#define IN_H   1024
#define IN_W   1024
#define TILE_X 128
#define TILE_Y 32
#define LDS_H  38     // TILE_Y + 6
#define LDS_W  136    // TILE_X + 6 halo, padded to multiple of 4 floats (34 float4)
#define ROW_F4 34

__global__ __launch_bounds__(256)
void conv7x7_kernel(const float* __restrict__ X,
                    const float* __restrict__ W,
                    float* __restrict__ out) {
    __shared__ float lds[LDS_H * LDS_W];

    const int tid = threadIdx.x;
    const int x0  = blockIdx.x * TILE_X;
    const int y0  = blockIdx.y * TILE_Y;
    const int b   = blockIdx.z;

    const float* Ximg = X + (size_t)b * IN_H * IN_W;

    // LDS col 0 = global col x0-4 (one extra col left of the 3-halo, for float4 alignment)
    // LDS row 0 = global row y0-3
    const int gx = x0 - 4;
    const int gy = y0 - 3;

    const bool interior = (gx >= 0) && (gx + LDS_W <= IN_W) &&
                          (gy >= 0) && (gy + LDS_H <= IN_H);

    if (interior) {
        for (int i = tid; i < LDS_H * ROW_F4; i += 256) {
            int r = i / ROW_F4;
            int c = i - r * ROW_F4;
            float4 v = *(const float4*)(Ximg + (gy + r) * IN_W + gx + c * 4);
            *(float4*)&lds[r * LDS_W + c * 4] = v;
        }
    } else {
        for (int i = tid; i < LDS_H * ROW_F4; i += 256) {
            int r   = i / ROW_F4;
            int c   = i - r * ROW_F4;
            int row = gy + r;
            float4 v = make_float4(0.f, 0.f, 0.f, 0.f);
            if (row >= 0 && row < IN_H) {
                const float* p = Ximg + row * IN_W;
                int col = gx + c * 4;
                v.x = (col + 0 >= 0 && col + 0 < IN_W) ? p[col + 0] : 0.f;
                v.y = (col + 1 >= 0 && col + 1 < IN_W) ? p[col + 1] : 0.f;
                v.z = (col + 2 >= 0 && col + 2 < IN_W) ? p[col + 2] : 0.f;
                v.w = (col + 3 >= 0 && col + 3 < IN_W) ? p[col + 3] : 0.f;
            }
            *(float4*)&lds[r * LDS_W + c * 4] = v;
        }
    }

    // Weights: uniform reads -> scalar loads / SGPRs
    float w[49];
    #pragma unroll
    for (int k = 0; k < 49; ++k) w[k] = W[k];

    __syncthreads();

    const int tx  = tid & 31;   // 32 thread-columns, each 4 outputs wide
    const int tyq = tid >> 5;   // 8 thread-rows, each 4 outputs tall

    float acc[4][4];
    #pragma unroll
    for (int o = 0; o < 4; ++o)
        #pragma unroll
        for (int c = 0; c < 4; ++c) acc[o][c] = 0.f;

    const int base_col = tx * 4;

    #pragma unroll
    for (int r = 0; r < 10; ++r) {   // 10 input rows feed 4 output rows
        const float* row = &lds[(tyq * 4 + r) * LDS_W + base_col];
        // three aligned 16B LDS reads -> s[0..11]; needed window is s[1..10]
        float4 a = *(const float4*)(row);
        float4 bq = *(const float4*)(row + 4);
        float4 cq = *(const float4*)(row + 8);
        float s[12] = { a.x, a.y, a.z, a.w,
                        bq.x, bq.y, bq.z, bq.w,
                        cq.x, cq.y, cq.z, cq.w };
        #pragma unroll
        for (int o = 0; o < 4; ++o) {
            const int ky = r - o;
            if (ky >= 0 && ky < 7) {
                #pragma unroll
                for (int kx = 0; kx < 7; ++kx) {
                    const float wv = w[ky * 7 + kx];
                    #pragma unroll
                    for (int c = 0; c < 4; ++c)
                        acc[o][c] += wv * s[1 + c + kx];
                }
            }
        }
    }

    float* Oimg = out + (size_t)b * IN_H * IN_W;
    const int ox = x0 + tx * 4;
    #pragma unroll
    for (int o = 0; o < 4; ++o) {
        const int oy = y0 + tyq * 4 + o;
        float4 v = make_float4(acc[o][0], acc[o][1], acc[o][2], acc[o][3]);
        *(float4*)(Oimg + (size_t)oy * IN_W + ox) = v;
    }
}

extern "C" void kernel_launch(void* const* d_in, const int* in_sizes, int n_in,
                              void* d_out, int out_size, void* d_ws, size_t ws_size,
                              hipStream_t stream) {
    const float* X = (const float*)d_in[0];
    const float* W = (const float*)d_in[1];
    float* out = (float*)d_out;

    dim3 grid(IN_W / TILE_X, IN_H / TILE_Y, 64);
    conv7x7_kernel<<<grid, 256, 0, stream>>>(X, W, out);
}